// Round 1
// baseline (41.416 us; speedup 1.0000x reference)
//
#include <hip/hip_runtime.h>
#include <math.h>

// out[c*65536 + pix] = in[(rho(pix)*256 + th(pix))*512 + c] * WSUM
// in : (1,256,256,512) f32 NHWC-flat ; out: same element count, warped-(C,H,W) flat.

__global__ __launch_bounds__(256) void InverseLogPolar_kernel(
        const float* __restrict__ in, float* __restrict__ out) {
    __shared__ int sBase[256];
    const int t    = threadIdx.x;
    const int pix0 = blockIdx.x << 8;   // 256 pixels per block
    const int c0   = blockIdx.y << 6;   // 64 channels per block

    // ---- inverse log-polar index, float64, mirrors numpy op-for-op ----
    {
        const int g = pix0 + t;
        const int i = g >> 8;
        const int j = g & 255;
        const double dy = (double)i - 127.5;
        const double dx = (double)j - 127.5;
        const double r  = sqrt(dx * dx + dy * dy);
        const double rmax  = sqrt(127.5 * 127.5 + 127.5 * 127.5);
        const double lrmax = log(rmax);
        double rho   = (r > 0.5) ? (log(fmax(r, 1e-6)) / lrmax) * 255.0 : 0.0;
        double theta = ((atan2(dy, dx) + M_PI) / (2.0 * M_PI)) * 255.0;
        double rr = fmin(fmax(rint(rho),   0.0), 255.0);
        double tt = fmin(fmax(rint(theta), 0.0), 255.0);
        const int rho_i = (int)rr;
        const int th_i  = (int)tt;
        sBase[t] = (rho_i << 17) | (th_i << 9);   // (rho*256 + th) * 512
    }
    __syncthreads();

    const int l = t & 63;        // lane
    const int w = t >> 6;        // wave in block
    const int4 b4 = *reinterpret_cast<const int4*>(&sBase[l << 2]);
    const float WSUM = (float)(0.2989 + 0.587 + 0.114);
    const int pl = pix0 + (l << 2);   // global pixel base for this thread's 4 pixels

    #pragma unroll
    for (int itc = 0; itc < 4; ++itc) {
        const int c = c0 + (w << 4) + (itc << 2);   // wave-uniform channel base
        const float4 v0 = *reinterpret_cast<const float4*>(in + b4.x + c);
        const float4 v1 = *reinterpret_cast<const float4*>(in + b4.y + c);
        const float4 v2 = *reinterpret_cast<const float4*>(in + b4.z + c);
        const float4 v3 = *reinterpret_cast<const float4*>(in + b4.w + c);

        float4 o0 = make_float4(v0.x * WSUM, v1.x * WSUM, v2.x * WSUM, v3.x * WSUM);
        float4 o1 = make_float4(v0.y * WSUM, v1.y * WSUM, v2.y * WSUM, v3.y * WSUM);
        float4 o2 = make_float4(v0.z * WSUM, v1.z * WSUM, v2.z * WSUM, v3.z * WSUM);
        float4 o3 = make_float4(v0.w * WSUM, v1.w * WSUM, v2.w * WSUM, v3.w * WSUM);

        *reinterpret_cast<float4*>(out + ((size_t)(c + 0) << 16) + pl) = o0;
        *reinterpret_cast<float4*>(out + ((size_t)(c + 1) << 16) + pl) = o1;
        *reinterpret_cast<float4*>(out + ((size_t)(c + 2) << 16) + pl) = o2;
        *reinterpret_cast<float4*>(out + ((size_t)(c + 3) << 16) + pl) = o3;
    }
}

extern "C" void kernel_launch(void* const* d_in, const int* in_sizes, int n_in,
                              void* d_out, int out_size, void* d_ws, size_t ws_size,
                              hipStream_t stream) {
    const float* in = (const float*)d_in[0];
    float* out = (float*)d_out;
    dim3 grid(256, 8);   // 256 pixel-tiles x 8 channel-tiles
    dim3 block(256);
    hipLaunchKernelGGL(InverseLogPolar_kernel, grid, block, 0, stream, in, out);
}

// Round 3
// 40.264 us; speedup vs baseline: 1.0286x; 1.0286x over previous
//
#include <hip/hip_runtime.h>
#include <math.h>

// out[c*65536 + pix] = in[(rho(pix)*256 + th(pix))*512 + c] * WSUM
// in : (1,256,256,512) f32 NHWC-flat ; out: same element count, warped-(C,H,W) flat.
// v3: non-temporal stores via native clang vector type (HIP_vector_type rejected
// by __builtin_nontemporal_store).

typedef float v4f __attribute__((ext_vector_type(4)));

__global__ __launch_bounds__(256) void InverseLogPolar_kernel(
        const float* __restrict__ in, float* __restrict__ out) {
    __shared__ int sBase[256];
    const int t    = threadIdx.x;
    const int pix0 = blockIdx.x << 8;   // 256 pixels per block
    const int c0   = blockIdx.y << 6;   // 64 channels per block

    // ---- inverse log-polar index, float64, mirrors numpy op-for-op ----
    {
        const int g = pix0 + t;
        const int i = g >> 8;
        const int j = g & 255;
        const double dy = (double)i - 127.5;
        const double dx = (double)j - 127.5;
        const double r  = sqrt(dx * dx + dy * dy);
        const double rmax  = sqrt(127.5 * 127.5 + 127.5 * 127.5);
        const double lrmax = log(rmax);
        double rho   = (r > 0.5) ? (log(fmax(r, 1e-6)) / lrmax) * 255.0 : 0.0;
        double theta = ((atan2(dy, dx) + M_PI) / (2.0 * M_PI)) * 255.0;
        double rr = fmin(fmax(rint(rho),   0.0), 255.0);
        double tt = fmin(fmax(rint(theta), 0.0), 255.0);
        const int rho_i = (int)rr;
        const int th_i  = (int)tt;
        sBase[t] = (rho_i << 17) | (th_i << 9);   // (rho*256 + th) * 512
    }
    __syncthreads();

    const int l = t & 63;        // lane
    const int w = t >> 6;        // wave in block
    const int4 b4 = *reinterpret_cast<const int4*>(&sBase[l << 2]);
    const float WSUM = (float)(0.2989 + 0.587 + 0.114);
    const int pl = pix0 + (l << 2);   // global pixel base for this thread's 4 pixels

    #pragma unroll
    for (int itc = 0; itc < 4; ++itc) {
        const int c = c0 + (w << 4) + (itc << 2);   // wave-uniform channel base
        const float4 v0 = *reinterpret_cast<const float4*>(in + b4.x + c);
        const float4 v1 = *reinterpret_cast<const float4*>(in + b4.y + c);
        const float4 v2 = *reinterpret_cast<const float4*>(in + b4.z + c);
        const float4 v3 = *reinterpret_cast<const float4*>(in + b4.w + c);

        v4f o0 = { v0.x * WSUM, v1.x * WSUM, v2.x * WSUM, v3.x * WSUM };
        v4f o1 = { v0.y * WSUM, v1.y * WSUM, v2.y * WSUM, v3.y * WSUM };
        v4f o2 = { v0.z * WSUM, v1.z * WSUM, v2.z * WSUM, v3.z * WSUM };
        v4f o3 = { v0.w * WSUM, v1.w * WSUM, v2.w * WSUM, v3.w * WSUM };

        __builtin_nontemporal_store(o0, reinterpret_cast<v4f*>(out + ((size_t)(c + 0) << 16) + pl));
        __builtin_nontemporal_store(o1, reinterpret_cast<v4f*>(out + ((size_t)(c + 1) << 16) + pl));
        __builtin_nontemporal_store(o2, reinterpret_cast<v4f*>(out + ((size_t)(c + 2) << 16) + pl));
        __builtin_nontemporal_store(o3, reinterpret_cast<v4f*>(out + ((size_t)(c + 3) << 16) + pl));
    }
}

extern "C" void kernel_launch(void* const* d_in, const int* in_sizes, int n_in,
                              void* d_out, int out_size, void* d_ws, size_t ws_size,
                              hipStream_t stream) {
    const float* in = (const float*)d_in[0];
    float* out = (float*)d_out;
    dim3 grid(256, 8);   // 256 pixel-tiles x 8 channel-tiles
    dim3 block(256);
    hipLaunchKernelGGL(InverseLogPolar_kernel, grid, block, 0, stream, in, out);
}

// Round 4
// 37.476 us; speedup vs baseline: 1.1051x; 1.0744x over previous
//
#include <hip/hip_runtime.h>
#include <math.h>

// out[c*65536 + pix] = in[(rho(pix)*256 + th(pix))*512 + c] * WSUM
// in : (1,256,256,512) f32 NHWC-flat ; out: warped-(C,H,W) flat f32.
// v4: LDS-transpose structure. Phase1 reads 128B-contiguous channel segments
// (8 runs per wave-instr instead of 64 scattered 16B), phase2 stores fully
// coalesced 1KB rows with nt. Tile = 32 channels x 256 pixels (one image row).

typedef float v4f __attribute__((ext_vector_type(4)));

__global__ __launch_bounds__(256) void InverseLogPolar_kernel(
        const float* __restrict__ in, float* __restrict__ out) {
    __shared__ int   sBase[256];
    __shared__ float tile[32 * 260];   // [ch][px], row stride 260 floats (16B-aligned, bank-rotated)

    const int t    = threadIdx.x;
    const int pix0 = blockIdx.x << 8;   // 256 pixels per block (one output row)
    const int c0   = blockIdx.y << 5;   // 32 channels per block

    // ---- inverse log-polar index, float64, mirrors numpy op-for-op ----
    {
        const int g = pix0 + t;
        const int i = g >> 8;
        const int j = g & 255;
        const double dy = (double)i - 127.5;
        const double dx = (double)j - 127.5;
        const double r  = sqrt(dx * dx + dy * dy);
        const double rmax  = sqrt(127.5 * 127.5 + 127.5 * 127.5);
        const double lrmax = log(rmax);
        double rho   = (r > 0.5) ? (log(fmax(r, 1e-6)) / lrmax) * 255.0 : 0.0;
        double theta = ((atan2(dy, dx) + M_PI) / (2.0 * M_PI)) * 255.0;
        double rr = fmin(fmax(rint(rho),   0.0), 255.0);
        double tt = fmin(fmax(rint(theta), 0.0), 255.0);
        sBase[t] = ((int)rr << 17) | ((int)tt << 9);   // (rho*256 + th) * 512
    }
    __syncthreads();

    const float WSUM = (float)(0.2989 + 0.587 + 0.114);

    // ---- phase 1: gather global -> LDS (transpose to [ch][px]) ----
    // 2048 chunks of 16B: chunk k -> pixel p = k>>3, channel offset cj = (k&7)*4.
    // Per wave-instr: lanes 0-7 share a pixel => 8 contiguous 128B runs.
    float4 v[8];
    #pragma unroll
    for (int it = 0; it < 8; ++it) {
        const int k = (it << 8) + t;
        const int p = k >> 3;
        const int cj = (k & 7) << 2;
        v[it] = *reinterpret_cast<const float4*>(in + sBase[p] + c0 + cj);
    }
    #pragma unroll
    for (int it = 0; it < 8; ++it) {
        const int k = (it << 8) + t;
        const int p = k >> 3;
        const int cj = (k & 7) << 2;
        tile[(cj + 0) * 260 + p] = v[it].x * WSUM;
        tile[(cj + 1) * 260 + p] = v[it].y * WSUM;
        tile[(cj + 2) * 260 + p] = v[it].z * WSUM;
        tile[(cj + 3) * 260 + p] = v[it].w * WSUM;
    }
    __syncthreads();

    // ---- phase 2: LDS -> global, fully coalesced 1KB per wave-instr ----
    const int l = t & 63;
    const int w = t >> 6;
    #pragma unroll
    for (int it2 = 0; it2 < 8; ++it2) {
        const int c = (w << 3) + it2;               // wave-uniform channel row
        const v4f o = *reinterpret_cast<const v4f*>(&tile[c * 260 + (l << 2)]);
        __builtin_nontemporal_store(
            o, reinterpret_cast<v4f*>(out + ((size_t)(c0 + c) << 16) + pix0 + (l << 2)));
    }
}

extern "C" void kernel_launch(void* const* d_in, const int* in_sizes, int n_in,
                              void* d_out, int out_size, void* d_ws, size_t ws_size,
                              hipStream_t stream) {
    const float* in = (const float*)d_in[0];
    float* out = (float*)d_out;
    dim3 grid(256, 16);   // 256 pixel rows x 16 channel tiles (32 ch each)
    dim3 block(256);
    hipLaunchKernelGGL(InverseLogPolar_kernel, grid, block, 0, stream, in, out);
}

// Round 5
// 32.927 us; speedup vs baseline: 1.2578x; 1.1382x over previous
//
#include <hip/hip_runtime.h>
#include <math.h>

// out[c*65536 + pix] = in[(rho(pix)*256 + th(pix))*512 + c] * WSUM
// in : (1,256,256,512) f32 NHWC-flat ; out: warped-(C,H,W) flat f32.
// v5: XCD-band swizzle. Gathered cells are shared across +-3 adjacent rows;
// keep a 32-row band resident on one XCD's L2 across all 16 channel tiles
// (per-tile footprint ~0.3-2MB << 4MB L2). HW: block b -> XCD b%8.

typedef float v4f __attribute__((ext_vector_type(4)));

__global__ __launch_bounds__(256) void InverseLogPolar_kernel(
        const float* __restrict__ in, float* __restrict__ out) {
    __shared__ int   sBase[256];
    __shared__ float tile[32 * 260];   // [ch][px], row stride 260 floats

    const int b    = blockIdx.x;
    const int row  = ((b & 7) << 5) | ((b >> 3) & 31);  // XCD k owns rows [32k, 32k+32)
    const int ct   = b >> 8;                            // channel tile 0..15
    const int t    = threadIdx.x;
    const int pix0 = row << 8;
    const int c0   = ct << 5;

    // ---- inverse log-polar index, float64, mirrors numpy op-for-op ----
    {
        const int i = row;
        const int j = t;
        const double dy = (double)i - 127.5;
        const double dx = (double)j - 127.5;
        const double r  = sqrt(dx * dx + dy * dy);
        const double rmax  = sqrt(127.5 * 127.5 + 127.5 * 127.5);
        const double lrmax = log(rmax);
        double rho   = (r > 0.5) ? (log(fmax(r, 1e-6)) / lrmax) * 255.0 : 0.0;
        double theta = ((atan2(dy, dx) + M_PI) / (2.0 * M_PI)) * 255.0;
        double rr = fmin(fmax(rint(rho),   0.0), 255.0);
        double tt = fmin(fmax(rint(theta), 0.0), 255.0);
        sBase[t] = ((int)rr << 17) | ((int)tt << 9);   // (rho*256 + th) * 512
    }
    __syncthreads();

    const float WSUM = (float)(0.2989 + 0.587 + 0.114);

    // ---- phase 1: gather global -> LDS (transpose to [ch][px]) ----
    // chunk k: pixel p = k>>3, channel offset cj = (k&7)*4  => lanes 0-7 share
    // a pixel: 8 contiguous 128B runs per wave-instruction.
    float4 v[8];
    #pragma unroll
    for (int it = 0; it < 8; ++it) {
        const int k = (it << 8) + t;
        const int p = k >> 3;
        const int cj = (k & 7) << 2;
        v[it] = *reinterpret_cast<const float4*>(in + sBase[p] + c0 + cj);
    }
    #pragma unroll
    for (int it = 0; it < 8; ++it) {
        const int k = (it << 8) + t;
        const int p = k >> 3;
        const int cj = (k & 7) << 2;
        tile[(cj + 0) * 260 + p] = v[it].x * WSUM;
        tile[(cj + 1) * 260 + p] = v[it].y * WSUM;
        tile[(cj + 2) * 260 + p] = v[it].z * WSUM;
        tile[(cj + 3) * 260 + p] = v[it].w * WSUM;
    }
    __syncthreads();

    // ---- phase 2: LDS -> global, fully coalesced 1KB per wave-instr ----
    const int l = t & 63;
    const int w = t >> 6;
    #pragma unroll
    for (int it2 = 0; it2 < 8; ++it2) {
        const int c = (w << 3) + it2;               // wave-uniform channel row
        const v4f o = *reinterpret_cast<const v4f*>(&tile[c * 260 + (l << 2)]);
        __builtin_nontemporal_store(
            o, reinterpret_cast<v4f*>(out + ((size_t)(c0 + c) << 16) + pix0 + (l << 2)));
    }
}

extern "C" void kernel_launch(void* const* d_in, const int* in_sizes, int n_in,
                              void* d_out, int out_size, void* d_ws, size_t ws_size,
                              hipStream_t stream) {
    const float* in = (const float*)d_in[0];
    float* out = (float*)d_out;
    dim3 grid(4096);    // 256 rows x 16 channel tiles, XCD-band swizzled
    dim3 block(256);
    hipLaunchKernelGGL(InverseLogPolar_kernel, grid, block, 0, stream, in, out);
}

// Round 6
// 32.489 us; speedup vs baseline: 1.2748x; 1.0135x over previous
//
#include <hip/hip_runtime.h>
#include <math.h>

// out[c*65536 + pix] = in[(rho(pix)*256 + th(pix))*512 + c] * WSUM
// in : (1,256,256,512) f32 NHWC-flat ; out: warped-(C,H,W) flat f32.
// v6: 64-ch x 256-px tiles (256B contiguous DRAM runs per gathered cell) +
// XOR-swizzled LDS transpose (2-way writes = free, conflict-free b128 reads).
// XCD-band swizzle kept: XCD k owns rows [32k,32k+32), sweeping 8 channel tiles.

typedef float v4f __attribute__((ext_vector_type(4)));

__global__ __launch_bounds__(256) void InverseLogPolar_kernel(
        const float* __restrict__ in, float* __restrict__ out) {
    __shared__ int   sBase[256];
    __shared__ float tile[64 * 256];   // [ch_row r][px p], addr = r*256 + (p ^ (((r>>2)&7)<<2))

    const int b    = blockIdx.x;
    const int row  = ((b & 7) << 5) | ((b >> 3) & 31);  // XCD k owns rows [32k, 32k+32)
    const int ct   = b >> 8;                            // channel tile 0..7
    const int t    = threadIdx.x;
    const int pix0 = row << 8;
    const int c0   = ct << 6;                           // 64 channels per block

    // ---- inverse log-polar index, float64, mirrors numpy op-for-op ----
    {
        const double dy = (double)row - 127.5;
        const double dx = (double)t   - 127.5;
        const double r  = sqrt(dx * dx + dy * dy);
        const double rmax  = sqrt(127.5 * 127.5 + 127.5 * 127.5);
        const double lrmax = log(rmax);
        double rho   = (r > 0.5) ? (log(fmax(r, 1e-6)) / lrmax) * 255.0 : 0.0;
        double theta = ((atan2(dy, dx) + M_PI) / (2.0 * M_PI)) * 255.0;
        double rr = fmin(fmax(rint(rho),   0.0), 255.0);
        double tt = fmin(fmax(rint(theta), 0.0), 255.0);
        sBase[t] = ((int)rr << 17) | ((int)tt << 9);   // (rho*256 + th) * 512
    }
    __syncthreads();

    const float WSUM = (float)(0.2989 + 0.587 + 0.114);

    // ---- phase 1: gather global -> registers ----
    // chunk k: pixel p = k>>4, channel offset cj = (k&15)*4.
    // 16 lanes per pixel => 256B contiguous run per gathered cell slice.
    float4 v[16];
    #pragma unroll
    for (int it = 0; it < 16; ++it) {
        const int k = (it << 8) + t;
        const int p = k >> 4;
        const int cj = (k & 15) << 2;
        v[it] = *reinterpret_cast<const float4*>(in + sBase[p] + c0 + cj);
    }
    // ---- registers -> LDS transpose (swizzled; 2-way bank = free) ----
    #pragma unroll
    for (int it = 0; it < 16; ++it) {
        const int k = (it << 8) + t;
        const int p = k >> 4;
        const int cj = (k & 15) << 2;
        const int pp = p ^ ((k & 7) << 2);   // ((r>>2)&7)<<2 with r=cj+d, d<4
        float* r0 = &tile[cj * 256 + pp];
        r0[0]       = v[it].x * WSUM;
        r0[256]     = v[it].y * WSUM;
        r0[512]     = v[it].z * WSUM;
        r0[768]     = v[it].w * WSUM;
    }
    __syncthreads();

    // ---- phase 2: LDS -> global, conflict-free b128, 1KB coalesced nt stores ----
    const int l = t & 63;
    const int w = t >> 6;
    #pragma unroll
    for (int it2 = 0; it2 < 16; ++it2) {
        const int c = (w << 4) + it2;                       // wave-uniform channel row
        const int pl = (l ^ ((c >> 2) & 7)) << 2;           // swizzled pixel group
        const v4f o = *reinterpret_cast<const v4f*>(&tile[c * 256 + pl]);
        __builtin_nontemporal_store(
            o, reinterpret_cast<v4f*>(out + ((size_t)(c0 + c) << 16) + pix0 + (pl ^ ((((c >> 2) & 7) << 2)))));
    }
}

extern "C" void kernel_launch(void* const* d_in, const int* in_sizes, int n_in,
                              void* d_out, int out_size, void* d_ws, size_t ws_size,
                              hipStream_t stream) {
    const float* in = (const float*)d_in[0];
    float* out = (float*)d_out;
    dim3 grid(2048);    // 256 rows x 8 channel tiles, XCD-band swizzled
    dim3 block(256);
    hipLaunchKernelGGL(InverseLogPolar_kernel, grid, block, 0, stream, in, out);
}